// Round 2
// baseline (355.348 us; speedup 1.0000x reference)
//
#include <hip/hip_runtime.h>

// Problem constants
#define LL    262144
#define GG    8
#define JJ    8
#define FGF   16
#define WW    31
#define PAD1  15
#define NB    4096           // k positions per block (big: amortize staging, fill CU)
#define NTHR  1024           // 16 waves/block; 2 blocks/CU = 32 waves = 100% slots
#define XTLEN (NB + 32)      // 4128 staged positions: x[nbase-16 .. nbase+NB+15]

typedef __bf16 bf16x8 __attribute__((ext_vector_type(8)));
typedef float  f32x4  __attribute__((ext_vector_type(4)));

__device__ inline unsigned short f2bf(float f) {
    unsigned int u = __float_as_uint(f);
    u = (u + 0x7FFF + ((u >> 16) & 1)) >> 16;   // RNE
    return (unsigned short)u;
}

// Y[16,L] = P[16,256]·XW[256,L] per group (K = 31w x 8j padded to 256).
// MFMA operands: A = X-fragment, B = P-fragment (swapped), so the D layout
// (m89-verified: col=lane&15, row=q*4+reg) gives each lane 4 CONSECUTIVE
// positions of one filter -> f32x4 coalesced stores.
// Rolling-window identity: frag(tile, s+4) == frag(tile+1, s) halves B-side
// LDS reads. LDS sized for 2 blocks/CU (72.5 KB): full wave-slot occupancy.
__global__ __launch_bounds__(NTHR, 8)
void conv_mfma(const float* __restrict__ x, const float* __restrict__ p,
               const int* __restrict__ rel, float* __restrict__ out)
{
    __shared__ unsigned short pw[32 * 16 * 8];   // [w][f][j] bf16, w=31 zeroed (8 KB)
    __shared__ unsigned short xt[XTLEN * 8];     // [pos][j]  bf16 (66 KB)

    const int t = threadIdx.x;
    const int g = blockIdx.y;
    const long nbase = (long)blockIdx.x * NB;

    // Hoist relation rows (uniform scalar loads).
    const long r0 = rel[g * JJ + 0], r1 = rel[g * JJ + 1];
    const long r2 = rel[g * JJ + 2], r3 = rel[g * JJ + 3];
    const long r4 = rel[g * JJ + 4], r5 = rel[g * JJ + 5];
    const long r6 = rel[g * JJ + 6], r7 = rel[g * JJ + 7];

    // ---- stage x: transpose-in-thread. One POSITION per thread per iter:
    // 8 coalesced scalar dword loads (one per row, 1MB-strided streams),
    // one aligned 16B ds_write_b128 (consecutive lanes -> consecutive 16B:
    // conflict-free; replaces the old 33K conflicted b16 scatter writes).
    {
        #pragma unroll
        for (int it = 0; it < (XTLEN + NTHR - 1) / NTHR; ++it) {   // 5 iters
            int c = t + it * NTHR;
            if (c < XTLEN) {
                long gp = nbase - 16 + c;
                unsigned int w0, w1, w2, w3;
                if (gp >= 0 && gp < LL) {
                    float v0 = x[r0 * LL + gp], v1 = x[r1 * LL + gp];
                    float v2 = x[r2 * LL + gp], v3 = x[r3 * LL + gp];
                    float v4 = x[r4 * LL + gp], v5 = x[r5 * LL + gp];
                    float v6 = x[r6 * LL + gp], v7 = x[r7 * LL + gp];
                    w0 = (unsigned int)f2bf(v0) | ((unsigned int)f2bf(v1) << 16);
                    w1 = (unsigned int)f2bf(v2) | ((unsigned int)f2bf(v3) << 16);
                    w2 = (unsigned int)f2bf(v4) | ((unsigned int)f2bf(v5) << 16);
                    w3 = (unsigned int)f2bf(v6) | ((unsigned int)f2bf(v7) << 16);
                } else {
                    w0 = w1 = w2 = w3 = 0u;     // halo outside [0, L)
                }
                uint4 pk; pk.x = w0; pk.y = w1; pk.z = w2; pk.w = w3;
                *(uint4*)&xt[c * 8] = pk;
            }
        }
    }

    // ---- stage P: linear LDS writes, scattered (L2-hot) global reads.
    {
        const float* pg = p + (long)g * FGF * JJ * WW;
        #pragma unroll
        for (int k = 0; k < 4; ++k) {
            int i = t + k * NTHR;            // i = (w*16 + f)*8 + j, 0..4095
            int w = i >> 7;
            int f = (i >> 3) & 15;
            int j = i & 7;
            float v = (w < WW) ? pg[(f * JJ + j) * WW + w] : 0.0f;
            pw[i] = f2bf(v);
        }
    }
    __syncthreads();

    const int lane = t & 63;
    const int wid  = t >> 6;      // wave 0..15, owns positions [wid*256, wid*256+256)
    const int col  = lane & 15;
    const int q    = lane >> 4;   // quad

    // P fragments (B operand): b[s] lane = P[g, f=col, j=0..7, w=s*4+q]
    bf16x8 b[8];
    #pragma unroll
    for (int s = 0; s < 8; ++s)
        b[s] = *(const bf16x8*)&pw[((s * 4 + q) * 16 + col) * 8];

    const int pb = wid * 256 + col + q + 1;   // lane's base xt position

    #define LDX(pos) (*(const bf16x8*)&xt[(pos) * 8])

    // Rolling window: F0 = frags(tile 2u, s=0..3)
    bf16x8 F00 = LDX(pb + 0), F01 = LDX(pb + 4), F02 = LDX(pb + 8), F03 = LDX(pb + 12);

    #pragma unroll
    for (int u = 0; u < 8; ++u) {
        const int o = pb + u * 32;
        // F1 = frags(2u, s=4..7) == frags(2u+1, s=0..3); F2 = frags(2u+1, s=4..7)
        bf16x8 F10 = LDX(o + 16), F11 = LDX(o + 20), F12 = LDX(o + 24), F13 = LDX(o + 28);
        bf16x8 F20 = LDX(o + 32), F21 = LDX(o + 36), F22 = LDX(o + 40), F23 = LDX(o + 44);

        f32x4 acc0 = {0.f, 0.f, 0.f, 0.f};
        f32x4 acc1 = {0.f, 0.f, 0.f, 0.f};
        acc0 = __builtin_amdgcn_mfma_f32_16x16x32_bf16(F00, b[0], acc0, 0, 0, 0);
        acc1 = __builtin_amdgcn_mfma_f32_16x16x32_bf16(F10, b[0], acc1, 0, 0, 0);
        acc0 = __builtin_amdgcn_mfma_f32_16x16x32_bf16(F01, b[1], acc0, 0, 0, 0);
        acc1 = __builtin_amdgcn_mfma_f32_16x16x32_bf16(F11, b[1], acc1, 0, 0, 0);
        acc0 = __builtin_amdgcn_mfma_f32_16x16x32_bf16(F02, b[2], acc0, 0, 0, 0);
        acc1 = __builtin_amdgcn_mfma_f32_16x16x32_bf16(F12, b[2], acc1, 0, 0, 0);
        acc0 = __builtin_amdgcn_mfma_f32_16x16x32_bf16(F03, b[3], acc0, 0, 0, 0);
        acc1 = __builtin_amdgcn_mfma_f32_16x16x32_bf16(F13, b[3], acc1, 0, 0, 0);
        acc0 = __builtin_amdgcn_mfma_f32_16x16x32_bf16(F10, b[4], acc0, 0, 0, 0);
        acc1 = __builtin_amdgcn_mfma_f32_16x16x32_bf16(F20, b[4], acc1, 0, 0, 0);
        acc0 = __builtin_amdgcn_mfma_f32_16x16x32_bf16(F11, b[5], acc0, 0, 0, 0);
        acc1 = __builtin_amdgcn_mfma_f32_16x16x32_bf16(F21, b[5], acc1, 0, 0, 0);
        acc0 = __builtin_amdgcn_mfma_f32_16x16x32_bf16(F12, b[6], acc0, 0, 0, 0);
        acc1 = __builtin_amdgcn_mfma_f32_16x16x32_bf16(F22, b[6], acc1, 0, 0, 0);
        acc0 = __builtin_amdgcn_mfma_f32_16x16x32_bf16(F13, b[7], acc0, 0, 0, 0);
        acc1 = __builtin_amdgcn_mfma_f32_16x16x32_bf16(F23, b[7], acc1, 0, 0, 0);

        // D layout: lane holds positions (tile*16 + q*4 .. +3) of filter `col`.
        const long kc0 = nbase + (long)(wid * 256 + u * 32) + q * 4;
        const size_t ro = (size_t)(g * FGF + col) * LL;
        *(f32x4*)&out[ro + kc0]      = acc0;    // tile 2u
        *(f32x4*)&out[ro + kc0 + 16] = acc1;    // tile 2u+1

        F00 = F20; F01 = F21; F02 = F22; F03 = F23;   // roll window
    }
    #undef LDX

    // ---- merged edge fix. Reference TRUNCATES the window at data edges
    // (not zero-pad): overwrite first/last 15 columns in exact fp32.
    // __syncthreads() drains the main loop's stores (vmcnt(0) before
    // s_barrier) so the overwrite cannot race with main-loop stores.
    if (blockIdx.x == 0 || blockIdx.x == (LL / NB - 1)) {
        __syncthreads();
        if (t < 256) {
            const int f  = t >> 4;
            const int qq = t & 15;
            if (qq < PAD1) {
                const bool left = (blockIdx.x == 0);
                float a = 0.0f;
                for (int j = 0; j < JJ; ++j) {
                    const float* pf = p + (((long)(g * FGF + f)) * JJ + j) * WW;
                    const float* xj = x + (long)rel[g * JJ + j] * LL + (left ? 0 : LL - WW);
                    #pragma unroll
                    for (int w = 0; w < WW; ++w) {
                        // left:  y[qq]      = sum_{w <= qq+15} x[w]      * K[w]
                        // right: y[L-15+qq] = sum_{w >= qq+1 } x[L-31+w] * K[w]
                        bool use = left ? (w <= qq + PAD1) : (w >= qq + 1);
                        if (use) a += xj[w] * pf[w];
                    }
                }
                const size_t ro = (size_t)(g * FGF + f) * LL;
                out[ro + (left ? (long)qq : (long)(LL - PAD1) + qq)] = a;
            }
        }
    }
}

extern "C" void kernel_launch(void* const* d_in, const int* in_sizes, int n_in,
                              void* d_out, int out_size, void* d_ws, size_t ws_size,
                              hipStream_t stream)
{
    const float* x   = (const float*)d_in[0];
    const float* p   = (const float*)d_in[1];
    const int*   rel = (const int*)d_in[2];
    float* out = (float*)d_out;

    dim3 grid(LL / NB, GG);   // (64, 8) = 512 blocks, 2/CU resident, one round
    conv_mfma<<<grid, NTHR, 0, stream>>>(x, p, rel, out);
}

// Round 3
// 215.809 us; speedup vs baseline: 1.6466x; 1.6466x over previous
//
#include <hip/hip_runtime.h>

// Problem constants
#define LL    262144
#define GG    8
#define JJ    8
#define FGF   16
#define WW    31
#define PAD1  15
#define NB    2048           // k positions per block
#define NTHR  512            // 8 waves/block; target 3 blocks/CU = 24 waves (75%)
#define XTLEN (NB + 32)      // 2080 staged positions: x[nbase-16 .. nbase+NB+15]

typedef __bf16 bf16x8 __attribute__((ext_vector_type(8)));
typedef float  f32x4  __attribute__((ext_vector_type(4)));

__device__ inline unsigned short f2bf(float f) {
    unsigned int u = __float_as_uint(f);
    u = (u + 0x7FFF + ((u >> 16) & 1)) >> 16;   // RNE
    return (unsigned short)u;
}

// Y[16,L] = P[16,256]·XW[256,L] per group (K = 31w x 8j padded to 256).
// MFMA operands: A = X-fragment, B = P-fragment (swapped), so D layout
// (m89-verified: col=lane&15 -> filter, row=q*4+reg -> position) gives each
// lane 4 CONSECUTIVE positions of one filter -> f32x4 coalesced stores.
//
// Register budget is the whole game (round-2 lesson: LB(1024,8) forced a
// 64-VGPR cap -> scratch spill -> +420 MB HBM traffic). Single-tile rolling
// window: F0 = frag(T, s=0..3), F1 = frag(T, s=4..7) == frag(T+1, s=0..3)
// -> 32 F regs + 32 b regs + 4 acc ~= 80 live, fits LB(512,6) cap of 85.
// LDS 40.5 KB -> 3 blocks/CU; 3 x 8 waves = 24/32 slots.
__global__ __launch_bounds__(NTHR, 6)
void conv_mfma(const float* __restrict__ x, const float* __restrict__ p,
               const int* __restrict__ rel, float* __restrict__ out)
{
    __shared__ unsigned short pw[32 * 16 * 8];   // [w][f][j] bf16, w=31 zeroed (8 KB)
    __shared__ unsigned short xt[XTLEN * 8];     // [pos][j]  bf16 (32.5 KB)

    const int t = threadIdx.x;
    const int g = blockIdx.y;
    const long nbase = (long)blockIdx.x * NB;

    // Hoist relation rows (uniform scalar loads).
    const long r0 = rel[g * JJ + 0], r1 = rel[g * JJ + 1];
    const long r2 = rel[g * JJ + 2], r3 = rel[g * JJ + 3];
    const long r4 = rel[g * JJ + 4], r5 = rel[g * JJ + 5];
    const long r6 = rel[g * JJ + 6], r7 = rel[g * JJ + 7];

    // ---- stage x: transpose-in-thread. One POSITION per thread per iter:
    // 8 coalesced scalar dword loads (one per row), one aligned 16B
    // ds_write_b128 (consecutive lanes -> consecutive 16B: conflict-free;
    // round-2 measured SQ_LDS_BANK_CONFLICT == 0 with this pattern).
    {
        #pragma unroll
        for (int it = 0; it < (XTLEN + NTHR - 1) / NTHR; ++it) {   // 5 iters
            int c = t + it * NTHR;
            if (c < XTLEN) {
                long gp = nbase - 16 + c;
                unsigned int w0, w1, w2, w3;
                if (gp >= 0 && gp < LL) {
                    float v0 = x[r0 * LL + gp], v1 = x[r1 * LL + gp];
                    float v2 = x[r2 * LL + gp], v3 = x[r3 * LL + gp];
                    float v4 = x[r4 * LL + gp], v5 = x[r5 * LL + gp];
                    float v6 = x[r6 * LL + gp], v7 = x[r7 * LL + gp];
                    w0 = (unsigned int)f2bf(v0) | ((unsigned int)f2bf(v1) << 16);
                    w1 = (unsigned int)f2bf(v2) | ((unsigned int)f2bf(v3) << 16);
                    w2 = (unsigned int)f2bf(v4) | ((unsigned int)f2bf(v5) << 16);
                    w3 = (unsigned int)f2bf(v6) | ((unsigned int)f2bf(v7) << 16);
                } else {
                    w0 = w1 = w2 = w3 = 0u;     // halo outside [0, L)
                }
                uint4 pk; pk.x = w0; pk.y = w1; pk.z = w2; pk.w = w3;
                *(uint4*)&xt[c * 8] = pk;
            }
        }
    }

    // ---- stage P: linear LDS writes, scattered (L2-hot) global reads.
    {
        const float* pg = p + (long)g * FGF * JJ * WW;
        #pragma unroll
        for (int k = 0; k < 8; ++k) {
            int i = t + k * NTHR;            // i = (w*16 + f)*8 + j, 0..4095
            int w = i >> 7;
            int f = (i >> 3) & 15;
            int j = i & 7;
            float v = (w < WW) ? pg[(f * JJ + j) * WW + w] : 0.0f;
            pw[i] = f2bf(v);
        }
    }
    __syncthreads();

    const int lane = t & 63;
    const int wid  = t >> 6;      // wave 0..7, owns positions [wid*256, wid*256+256)
    const int col  = lane & 15;
    const int q    = lane >> 4;   // quad

    // P fragments (B operand): b[s] lane = P[g, f=col, j=0..7, w=s*4+q]
    bf16x8 b[8];
    #pragma unroll
    for (int s = 0; s < 8; ++s)
        b[s] = *(const bf16x8*)&pw[((s * 4 + q) * 16 + col) * 8];

    const int pb = wid * 256 + col + q + 1;   // lane's base xt position

    #define LDX(pos) (*(const bf16x8*)&xt[(pos) * 8])

    // frag(T, s) = LDX(pb + T*16 + s*4); identity frag(T, s+4) == frag(T+1, s)
    bf16x8 F0a = LDX(pb + 0), F0b = LDX(pb + 4), F0c = LDX(pb + 8), F0d = LDX(pb + 12);

    #pragma unroll
    for (int T = 0; T < 16; ++T) {
        const int o = pb + T * 16 + 16;
        bf16x8 F1a = LDX(o + 0), F1b = LDX(o + 4), F1c = LDX(o + 8), F1d = LDX(o + 12);

        f32x4 acc = {0.f, 0.f, 0.f, 0.f};
        acc = __builtin_amdgcn_mfma_f32_16x16x32_bf16(F0a, b[0], acc, 0, 0, 0);
        acc = __builtin_amdgcn_mfma_f32_16x16x32_bf16(F0b, b[1], acc, 0, 0, 0);
        acc = __builtin_amdgcn_mfma_f32_16x16x32_bf16(F0c, b[2], acc, 0, 0, 0);
        acc = __builtin_amdgcn_mfma_f32_16x16x32_bf16(F0d, b[3], acc, 0, 0, 0);
        acc = __builtin_amdgcn_mfma_f32_16x16x32_bf16(F1a, b[4], acc, 0, 0, 0);
        acc = __builtin_amdgcn_mfma_f32_16x16x32_bf16(F1b, b[5], acc, 0, 0, 0);
        acc = __builtin_amdgcn_mfma_f32_16x16x32_bf16(F1c, b[6], acc, 0, 0, 0);
        acc = __builtin_amdgcn_mfma_f32_16x16x32_bf16(F1d, b[7], acc, 0, 0, 0);

        // D layout: lane holds positions (T*16 + q*4 .. +3) of filter `col`.
        const long kc0 = nbase + (long)(wid * 256 + T * 16) + q * 4;
        const size_t ro = (size_t)(g * FGF + col) * LL;
        *(f32x4*)&out[ro + kc0] = acc;

        F0a = F1a; F0b = F1b; F0c = F1c; F0d = F1d;   // roll window
    }
    #undef LDX

    // ---- merged edge fix. Reference TRUNCATES the window at data edges
    // (not zero-pad): overwrite first/last 15 columns in exact fp32.
    // __syncthreads() drains this block's main-loop stores first; only this
    // block writes these columns, so no cross-block ordering is needed.
    if (blockIdx.x == 0 || blockIdx.x == (LL / NB - 1)) {
        __syncthreads();
        if (t < 256) {
            const int f  = t >> 4;
            const int qq = t & 15;
            if (qq < PAD1) {
                const bool left = (blockIdx.x == 0);
                float a = 0.0f;
                for (int j = 0; j < JJ; ++j) {
                    const float* pf = p + (((long)(g * FGF + f)) * JJ + j) * WW;
                    const float* xj = x + (long)rel[g * JJ + j] * LL + (left ? 0 : LL - WW);
                    #pragma unroll
                    for (int w = 0; w < WW; ++w) {
                        // left:  y[qq]      = sum_{w <= qq+15} x[w]      * K[w]
                        // right: y[L-15+qq] = sum_{w >= qq+1 } x[L-31+w] * K[w]
                        bool use = left ? (w <= qq + PAD1) : (w >= qq + 1);
                        if (use) a += xj[w] * pf[w];
                    }
                }
                const size_t ro = (size_t)(g * FGF + f) * LL;
                out[ro + (left ? (long)qq : (long)(LL - PAD1) + qq)] = a;
            }
        }
    }
}

extern "C" void kernel_launch(void* const* d_in, const int* in_sizes, int n_in,
                              void* d_out, int out_size, void* d_ws, size_t ws_size,
                              hipStream_t stream)
{
    const float* x   = (const float*)d_in[0];
    const float* p   = (const float*)d_in[1];
    const int*   rel = (const int*)d_in[2];
    float* out = (float*)d_out;

    dim3 grid(LL / NB, GG);   // (128, 8) = 1024 blocks
    conv_mfma<<<grid, NTHR, 0, stream>>>(x, p, rel, out);
}